// Round 9
// baseline (55.627 us; speedup 1.0000x reference)
//
#include <hip/hip_runtime.h>
#include <cstdint>

#define DEVFN __device__ __forceinline__

struct U128 { unsigned long long lo, hi; };

// rotate right by s (1..127): bit q of result = bit (q+s)%128 of w
DEVFN U128 rotr128(U128 w, int s) {
    U128 r;
    if (s == 64) { r.lo = w.hi; r.hi = w.lo; return r; }
    if (s < 64) {
        r.lo = (w.lo >> s) | (w.hi << (64 - s));
        r.hi = (w.hi >> s) | (w.lo << (64 - s));
    } else {
        int t = s - 64;
        unsigned long long lo = w.hi, hi = w.lo;
        r.lo = (lo >> t) | (hi << (64 - t));
        r.hi = (hi >> t) | (lo << (64 - t));
    }
    return r;
}

// logical shift right by s (1..127)
DEVFN U128 shr128(U128 w, int s) {
    U128 r;
    if (s == 64) { r.lo = w.hi; r.hi = 0ull; return r; }
    if (s < 64) {
        r.lo = (w.lo >> s) | (w.hi << (64 - s));
        r.hi = w.hi >> s;
    } else {
        r.lo = w.hi >> (s - 64); r.hi = 0ull;
    }
    return r;
}

// KB: W0 reduction (768 blocks) + S/counter-init (block 768). Compute path
// byte-identical to R8.
__global__ __launch_bounds__(256) void kB(const int* __restrict__ x,
                                          const int* __restrict__ masks,
                                          const float* __restrict__ W0,
                                          float* __restrict__ S,
                                          float* __restrict__ A2,
                                          float* __restrict__ G2,
                                          int* __restrict__ cnt) {
    int bid = blockIdx.x;
    int tid = threadIdx.x;

    if (bid == 768) {
        if (tid < 36) cnt[tid] = 0;          // cnt[0..31]=per-(hc,bs), cnt[32..35]=per-bs
        int b = tid >> 2;        // 64 rows of x
        int rc = tid & 3;        // 4 chunks of 32 r's
        const int* xb = x + b * 128;
        U128 w; w.lo = 0ull; w.hi = 0ull;
        #pragma unroll
        for (int p = 0; p < 64; ++p) w.lo |= (unsigned long long)(xb[p] & 1) << p;
        #pragma unroll
        for (int p = 0; p < 64; ++p) w.hi |= (unsigned long long)(xb[64 + p] & 1) << p;
        int r0 = rc * 32;
        if (r0 & 32) { U128 t = rotr128(w, 32); w.lo ^= t.lo; w.hi ^= t.hi; }
        if (r0 & 64) { U128 t = rotr128(w, 64); w.lo ^= t.lo; w.hi ^= t.hi; }
        for (int rr = 0; rr < 32; ++rr) {
            int r = r0 + rr;
            int pc = __popcll(w.lo) + __popcll(w.hi);
            int sv = (r == 0) ? pc : (128 - pc);
            S[b * 128 + r] = (float)(2 * sv);
            U128 t = rotr128(w, 1);
            w.lo ^= t.lo; w.hi ^= t.hi;
        }
        return;
    }

    int hc = bid & 3;            // 4 quarters of 256 h
    int y  = bid >> 2;           // 0..191 (r, segment) task
    int r, jstart, jend, slice;
    if (y < 128) { r = y >> 1; slice = y & 1; jstart = slice * 64; jend = (slice == 0) ? 64 : (128 - r); }
    else         { r = y - 64;  slice = 0;    jstart = 0;          jend = 128 - r; }
    int L = jend - jstart;       // 1..64

    int lane = tid & 63;
    int g    = tid >> 6;         // row-group 0..3

    __shared__ unsigned long long mw[3][2];
    __shared__ float cA[64], cG[64];
    __shared__ float4 partA[4][64];
    __shared__ float4 partG[4][64];

    if (tid < 128) {
        int half = tid >> 6;
        int lane_ = tid & 63;
        #pragma unroll
        for (int k = 0; k < 3; ++k) {
            unsigned long long bal = __ballot(masks[k * 128 + half * 64 + lane_] & 1);
            if (lane_ == 0) mw[k][half] = bal;
        }
    }
    __syncthreads();
    if (tid < 64) {
        int j = jstart + tid;
        int c = 0;
        #pragma unroll
        for (int k = 0; k < 3; ++k) {
            U128 m; m.lo = mw[k][0]; m.hi = mw[k][1];
            #pragma unroll
            for (int s = 1; s <= 64; s <<= 1) {
                if (r & s) { U128 t = shr128(m, s); m.lo ^= t.lo; m.hi ^= t.hi; }
            }
            int bit = (j < 64) ? (int)((m.lo >> j) & 1) : (int)((m.hi >> (j - 64)) & 1);
            c += bit;
        }
        cA[tid] = 0.5f * (float)c - 1.0f;
        cG[tid] = (float)(2 - c) * (1.0f / 256.0f);
    }
    __syncthreads();

    int off = r * 128 - (r * (r - 1)) / 2;
    const float* base = W0 + (size_t)(off + jstart) * 1024 + hc * 256 + lane * 4;
    float4 aA = {0.f, 0.f, 0.f, 0.f}, aG = {0.f, 0.f, 0.f, 0.f};
    #pragma unroll 4
    for (int jj = g; jj < L; jj += 4) {
        float4 v = *(const float4*)(base + (size_t)jj * 1024);
        float ca = cA[jj], cg = cG[jj];
        aA.x += ca * v.x; aA.y += ca * v.y; aA.z += ca * v.z; aA.w += ca * v.w;
        aG.x += cg * v.x; aG.y += cg * v.y; aG.z += cg * v.z; aG.w += cg * v.w;
    }
    partA[g][lane] = aA;
    partG[g][lane] = aG;
    __syncthreads();

    if (tid < 64) {
        float4 sA = partA[0][tid], sG = partG[0][tid];
        #pragma unroll
        for (int gg = 1; gg < 4; ++gg) {
            float4 pA = partA[gg][tid], pG = partG[gg][tid];
            sA.x += pA.x; sA.y += pA.y; sA.z += pA.z; sA.w += pA.w;
            sG.x += pG.x; sG.y += pG.y; sG.z += pG.z; sG.w += pG.w;
        }
        int row = slice * 128 + r;
        *(float4*)(A2 + (size_t)row * 1024 + hc * 256 + tid * 4) = sA;
        *(float4*)(G2 + (size_t)row * 1024 + hc * 256 + tid * 4) = sG;
    }
}

// kFE: fused layer-1 + layer-2 split-K (compute identical to R8 kF) with
// last-arriver reduction replacing the kE node. No spinning: non-last blocks
// exit; the 16th kc-block per (hc,bs) reduces z1part, applies b1/relu/Wo and
// writes outpart[hc][b]; the 8th hc-cleanup per bs writes out. All reduction
// loops are fixed-order -> bitwise deterministic.
__global__ __launch_bounds__(256) void kFE(const float* __restrict__ A2,
                                           const float* __restrict__ G2,
                                           const float* __restrict__ S,
                                           const float* __restrict__ b0,
                                           const float* __restrict__ W1,
                                           const float* __restrict__ b1,
                                           const float* __restrict__ Wo,
                                           const float* __restrict__ bo,
                                           float* __restrict__ z1part,
                                           float* __restrict__ outpart,
                                           int* __restrict__ cnt,
                                           float* __restrict__ out) {
    int hc = blockIdx.x;          // 0..7   (128 h-cols each)
    int kc = blockIdx.y;          // 0..15  (64 k each)
    int bs = blockIdx.z;          // 0..3   (16 b each)
    int tid = threadIdx.x;

    __shared__ float W1sh[64][128];   // 32 KB
    __shared__ float Ssh[16][128];    // 8 KB
    __shared__ float h0sh[16][64];    // 4 KB
    __shared__ float wred[2][2][8];
    __shared__ int bc1, bc2;

    #pragma unroll
    for (int t = 0; t < 32; ++t) {
        int idx = tid + t * 256;      // 0..8191
        int kk = idx >> 7, hcl = idx & 127;
        W1sh[kk][hcl] = W1[(kc * 64 + kk) * 1024 + hc * 128 + hcl];
    }
    #pragma unroll
    for (int t = 0; t < 8; ++t) {
        int idx = tid + t * 256;      // 0..2047
        int bl = idx >> 7, r = idx & 127;
        Ssh[bl][r] = S[(bs * 16 + bl) * 128 + r];
    }
    __syncthreads();

    // ---- Phase A: h0 sub-tile ----
    {
        int k = tid & 63;
        int bg = tid >> 6;
        const float* a2p = A2 + kc * 64 + k;
        const float* g2p = G2 + kc * 64 + k;
        float accA = 0.f;
        float acc[4] = {0.f, 0.f, 0.f, 0.f};
        #pragma unroll 8
        for (int row = 0; row < 192; ++row) {
            float a = a2p[row * 1024];
            float g = g2p[row * 1024];
            accA += a;
            int r = row & 127;
            #pragma unroll
            for (int bb = 0; bb < 4; ++bb)
                acc[bb] += Ssh[bg * 4 + bb][r] * g;
        }
        float base = b0[kc * 64 + k] + accA;
        #pragma unroll
        for (int bb = 0; bb < 4; ++bb)
            h0sh[bg * 4 + bb][k] = fmaxf(base + acc[bb], 0.f);
    }
    __syncthreads();

    // ---- Phase B: z1part tile ----
    {
        int hcol = tid & 127;
        int bg2 = tid >> 7;
        float acc2[8];
        #pragma unroll
        for (int i = 0; i < 8; ++i) acc2[i] = 0.f;
        #pragma unroll 4
        for (int kk = 0; kk < 64; ++kk) {
            float w = W1sh[kk][hcol];
            #pragma unroll
            for (int bb = 0; bb < 8; ++bb)
                acc2[bb] += h0sh[bg2 * 8 + bb][kk] * w;
        }
        #pragma unroll
        for (int bb = 0; bb < 8; ++bb) {
            int b = bs * 16 + bg2 * 8 + bb;
            z1part[(kc * 64 + b) * 1024 + hc * 128 + hcol] = acc2[bb];
        }
    }
    __syncthreads();

    // ---- last-arriver stage 1: per (hc,bs), 16 kc producers ----
    if (tid == 0) {
        __threadfence();                               // release z1part writes
        int old = atomicAdd(&cnt[hc * 4 + bs], 1);
        bc1 = (old == 15);
        if (bc1) __threadfence();                      // acquire others' writes
    }
    __syncthreads();
    if (!bc1) return;

    // cleanup: z1[b][h] over 16 kc, relu, dot with Wo slice -> outpart[hc][b]
    {
        int h = tid & 127;
        int half = tid >> 7;                           // 2 halves of 8 b
        int hglob = hc * 128 + h;
        float wo = Wo[hglob];
        float bb1 = b1[hglob];
        int wv = (tid >> 6) & 1;
        #pragma unroll
        for (int bl = 0; bl < 8; ++bl) {
            int b = bs * 16 + half * 8 + bl;
            float z = bb1;
            #pragma unroll
            for (int kc2 = 0; kc2 < 16; ++kc2)
                z += z1part[(kc2 * 64 + b) * 1024 + hglob];
            float v = fmaxf(z, 0.f) * wo;
            #pragma unroll
            for (int offv = 32; offv >= 1; offv >>= 1) v += __shfl_down(v, offv);
            if ((tid & 63) == 0) wred[half][wv][bl] = v;
        }
    }
    __syncthreads();
    if (tid < 16) {
        int half2 = tid >> 3, bl2 = tid & 7;
        outpart[hc * 64 + bs * 16 + half2 * 8 + bl2] =
            wred[half2][0][bl2] + wred[half2][1][bl2];
    }
    __syncthreads();

    // ---- last-arriver stage 2: per bs, 8 hc cleanups ----
    if (tid == 0) {
        __threadfence();                               // release outpart writes
        int old2 = atomicAdd(&cnt[32 + bs], 1);
        bc2 = (old2 == 7);
        if (bc2) __threadfence();                      // acquire others' outpart
    }
    __syncthreads();
    if (!bc2) return;

    if (tid < 16) {
        int b = bs * 16 + tid;
        float s = bo[0];
        #pragma unroll
        for (int hc2 = 0; hc2 < 8; ++hc2) s += outpart[hc2 * 64 + b];
        out[b] = s;
    }
}

extern "C" void kernel_launch(void* const* d_in, const int* in_sizes, int n_in,
                              void* d_out, int out_size, void* d_ws, size_t ws_size,
                              hipStream_t stream) {
    const int*   x     = (const int*)d_in[0];    // (64,128) 0/1
    const int*   masks = (const int*)d_in[1];    // (3,128) 0/1
    const float* W0    = (const float*)d_in[2];  // (8256,1024)
    const float* b0    = (const float*)d_in[3];  // (1024)
    const float* W1    = (const float*)d_in[4];  // (1024,1024)
    const float* b1    = (const float*)d_in[5];  // (1024)
    const float* Wo    = (const float*)d_in[6];  // (1024,1)
    const float* bo    = (const float*)d_in[7];  // (1)
    float* out = (float*)d_out;                  // (64,1)

    char* ws = (char*)d_ws;
    float* S       = (float*)(ws);                     // 64*128*4      = 32 KB
    float* A2      = (float*)(ws + (32u   << 10));     // 192*1024*4    = 768 KB
    float* G2      = (float*)(ws + (800u  << 10));     // 192*1024*4    = 768 KB
    float* z1part  = (float*)(ws + (1568u << 10));     // 16*64*1024*4  = 4 MB
    float* outpart = (float*)(ws + (5664u << 10));     // 8*64*4        = 2 KB
    int*   cnt     = (int*)  (ws + (5666u << 10));     // 36 ints

    kB<<<769, 256, 0, stream>>>(x, masks, W0, S, A2, G2, cnt);
    kFE<<<dim3(8, 16, 4), 256, 0, stream>>>(A2, G2, S, b0, W1, b1, Wo, bo,
                                            z1part, outpart, cnt, out);
}

// Round 10
// 33.734 us; speedup vs baseline: 1.6490x; 1.6490x over previous
//
#include <hip/hip_runtime.h>
#include <cstdint>

#define DEVFN __device__ __forceinline__

struct U128 { unsigned long long lo, hi; };

// rotate right by s (1..127): bit q of result = bit (q+s)%128 of w
DEVFN U128 rotr128(U128 w, int s) {
    U128 r;
    if (s == 64) { r.lo = w.hi; r.hi = w.lo; return r; }
    if (s < 64) {
        r.lo = (w.lo >> s) | (w.hi << (64 - s));
        r.hi = (w.hi >> s) | (w.lo << (64 - s));
    } else {
        int t = s - 64;
        unsigned long long lo = w.hi, hi = w.lo;
        r.lo = (lo >> t) | (hi << (64 - t));
        r.hi = (hi >> t) | (lo << (64 - t));
    }
    return r;
}

// logical shift right by s (1..127)
DEVFN U128 shr128(U128 w, int s) {
    U128 r;
    if (s == 64) { r.lo = w.hi; r.hi = 0ull; return r; }
    if (s < 64) {
        r.lo = (w.lo >> s) | (w.hi << (64 - s));
        r.hi = w.hi >> s;
    } else {
        r.lo = w.hi >> (s - 64); r.hi = 0ull;
    }
    return r;
}

// KB: W0 -> G2 reduction (768 blocks) + Sm computation (block 768).
// Uses the identity cA = -128*cG: only the G-weighted sums are needed;
// Sm[b][r] = S[b][r] - 128 is stored pre-shifted.
__global__ __launch_bounds__(256) void kB(const int* __restrict__ x,
                                          const int* __restrict__ masks,
                                          const float* __restrict__ W0,
                                          float* __restrict__ Sm,
                                          float* __restrict__ G2) {
    int bid = blockIdx.x;
    int tid = threadIdx.x;

    if (bid == 768) {
        int b = tid >> 2;        // 64 rows of x
        int rc = tid & 3;        // 4 chunks of 32 r's
        const int* xb = x + b * 128;
        U128 w; w.lo = 0ull; w.hi = 0ull;
        #pragma unroll
        for (int p = 0; p < 64; ++p) w.lo |= (unsigned long long)(xb[p] & 1) << p;
        #pragma unroll
        for (int p = 0; p < 64; ++p) w.hi |= (unsigned long long)(xb[64 + p] & 1) << p;
        int r0 = rc * 32;
        if (r0 & 32) { U128 t = rotr128(w, 32); w.lo ^= t.lo; w.hi ^= t.hi; }
        if (r0 & 64) { U128 t = rotr128(w, 64); w.lo ^= t.lo; w.hi ^= t.hi; }
        for (int rr = 0; rr < 32; ++rr) {
            int r = r0 + rr;
            int pc = __popcll(w.lo) + __popcll(w.hi);
            int sv = (r == 0) ? pc : (128 - pc);
            Sm[b * 128 + r] = (float)(2 * sv - 128);
            U128 t = rotr128(w, 1);
            w.lo ^= t.lo; w.hi ^= t.hi;
        }
        return;
    }

    int hc = bid & 3;            // 4 quarters of 256 h
    int y  = bid >> 2;           // 0..191 (r, segment) task
    int r, jstart, jend, slice;
    if (y < 128) { r = y >> 1; slice = y & 1; jstart = slice * 64; jend = (slice == 0) ? 64 : (128 - r); }
    else         { r = y - 64;  slice = 0;    jstart = 0;          jend = 128 - r; }
    int L = jend - jstart;       // 1..64

    int lane = tid & 63;
    int g    = tid >> 6;         // row-group 0..3

    __shared__ unsigned long long mw[3][2];
    __shared__ float cG[64];
    __shared__ float4 partG[4][64];

    if (tid < 128) {
        int half = tid >> 6;
        int lane_ = tid & 63;
        #pragma unroll
        for (int k = 0; k < 3; ++k) {
            unsigned long long bal = __ballot(masks[k * 128 + half * 64 + lane_] & 1);
            if (lane_ == 0) mw[k][half] = bal;
        }
    }
    __syncthreads();
    if (tid < 64) {
        int j = jstart + tid;
        int c = 0;
        #pragma unroll
        for (int k = 0; k < 3; ++k) {
            U128 m; m.lo = mw[k][0]; m.hi = mw[k][1];
            #pragma unroll
            for (int s = 1; s <= 64; s <<= 1) {
                if (r & s) { U128 t = shr128(m, s); m.lo ^= t.lo; m.hi ^= t.hi; }
            }
            int bit = (j < 64) ? (int)((m.lo >> j) & 1) : (int)((m.hi >> (j - 64)) & 1);
            c += bit;
        }
        cG[tid] = (float)(2 - c) * (1.0f / 256.0f);
    }
    __syncthreads();

    int off = r * 128 - (r * (r - 1)) / 2;
    const float* base = W0 + (size_t)(off + jstart) * 1024 + hc * 256 + lane * 4;
    float4 aG = {0.f, 0.f, 0.f, 0.f};
    #pragma unroll 4
    for (int jj = g; jj < L; jj += 4) {
        float4 v = *(const float4*)(base + (size_t)jj * 1024);
        float cg = cG[jj];
        aG.x += cg * v.x; aG.y += cg * v.y; aG.z += cg * v.z; aG.w += cg * v.w;
    }
    partG[g][lane] = aG;
    __syncthreads();

    if (tid < 64) {
        float4 sG = partG[0][tid];
        #pragma unroll
        for (int gg = 1; gg < 4; ++gg) {
            float4 pG = partG[gg][tid];
            sG.x += pG.x; sG.y += pG.y; sG.z += pG.z; sG.w += pG.w;
        }
        int row = slice * 128 + r;
        *(float4*)(G2 + (size_t)row * 1024 + hc * 256 + tid * 4) = sG;
    }
}

// kF: fused layer-1 + layer-2 split-K. 1-D grid of 512; kc = bid&15 so all 32
// blocks sharing a kc (same G2 columns + W1 rows) land on one XCD (bid%8).
// Phase A: h0[b][k] = relu(b0[k] + sum_row Sm[b][row&127] * G2[row][k])
// Phase B: z1part[kc][b][hc-slice] = h0 . W1tile
__global__ __launch_bounds__(256) void kF(const float* __restrict__ G2,
                                          const float* __restrict__ Sm,
                                          const float* __restrict__ b0,
                                          const float* __restrict__ W1,
                                          float* __restrict__ z1part) {
    int bid = blockIdx.x;
    int kc = bid & 15;            // 0..15  (64 k each)  -> XCD = kc&7
    int hc = (bid >> 4) & 7;      // 0..7   (128 h-cols each)
    int bs = bid >> 7;            // 0..3   (16 b each)
    int tid = threadIdx.x;

    __shared__ float W1sh[64][128];   // 32 KB
    __shared__ float Ssh[16][128];    // 8 KB (pre-shifted S - 128)
    __shared__ float h0sh[16][64];    // 4 KB

    #pragma unroll
    for (int t = 0; t < 32; ++t) {
        int idx = tid + t * 256;      // 0..8191
        int kk = idx >> 7, hcl = idx & 127;
        W1sh[kk][hcl] = W1[(kc * 64 + kk) * 1024 + hc * 128 + hcl];
    }
    #pragma unroll
    for (int t = 0; t < 8; ++t) {
        int idx = tid + t * 256;      // 0..2047
        int bl = idx >> 7, r = idx & 127;
        Ssh[bl][r] = Sm[(bs * 16 + bl) * 128 + r];
    }
    __syncthreads();

    // ---- Phase A: h0 sub-tile ----
    {
        int k = tid & 63;
        int bg = tid >> 6;
        const float* g2p = G2 + kc * 64 + k;
        float acc[4] = {0.f, 0.f, 0.f, 0.f};
        #pragma unroll 8
        for (int row = 0; row < 192; ++row) {
            float gv = g2p[row * 1024];
            int r = row & 127;
            #pragma unroll
            for (int bb = 0; bb < 4; ++bb)
                acc[bb] += Ssh[bg * 4 + bb][r] * gv;
        }
        float base = b0[kc * 64 + k];
        #pragma unroll
        for (int bb = 0; bb < 4; ++bb)
            h0sh[bg * 4 + bb][k] = fmaxf(base + acc[bb], 0.f);
    }
    __syncthreads();

    // ---- Phase B: z1part tile = h0sh (16x64) . W1sh (64x128) ----
    {
        int hcol = tid & 127;
        int bg2 = tid >> 7;
        float acc2[8];
        #pragma unroll
        for (int i = 0; i < 8; ++i) acc2[i] = 0.f;
        #pragma unroll 4
        for (int kk = 0; kk < 64; ++kk) {
            float w = W1sh[kk][hcol];
            #pragma unroll
            for (int bb = 0; bb < 8; ++bb)
                acc2[bb] += h0sh[bg2 * 8 + bb][kk] * w;
        }
        #pragma unroll
        for (int bb = 0; bb < 8; ++bb) {
            int b = bs * 16 + bg2 * 8 + bb;
            z1part[(kc * 64 + b) * 1024 + hc * 128 + hcol] = acc2[bb];
        }
    }
}

// kE: out[b] = sum_h relu(b1[h] + sum_kc z1part[kc][b][h]) * Wo[h] + bo
__global__ __launch_bounds__(1024) void kE(const float* __restrict__ z1part,
                                           const float* __restrict__ b1,
                                           const float* __restrict__ Wo,
                                           const float* __restrict__ bo,
                                           float* __restrict__ out) {
    int b = blockIdx.x;
    int h = threadIdx.x;
    float z = b1[h];
    #pragma unroll
    for (int kc = 0; kc < 16; ++kc) z += z1part[(kc * 64 + b) * 1024 + h];
    float acc = fmaxf(z, 0.f) * Wo[h];
    #pragma unroll
    for (int off = 32; off >= 1; off >>= 1) acc += __shfl_down(acc, off);
    __shared__ float red[16];
    if ((h & 63) == 0) red[h >> 6] = acc;
    __syncthreads();
    if (h == 0) {
        float s = bo[0];
        #pragma unroll
        for (int i = 0; i < 16; ++i) s += red[i];
        out[b] = s;
    }
}

extern "C" void kernel_launch(void* const* d_in, const int* in_sizes, int n_in,
                              void* d_out, int out_size, void* d_ws, size_t ws_size,
                              hipStream_t stream) {
    const int*   x     = (const int*)d_in[0];    // (64,128) 0/1
    const int*   masks = (const int*)d_in[1];    // (3,128) 0/1
    const float* W0    = (const float*)d_in[2];  // (8256,1024)
    const float* b0    = (const float*)d_in[3];  // (1024)
    const float* W1    = (const float*)d_in[4];  // (1024,1024)
    const float* b1    = (const float*)d_in[5];  // (1024)
    const float* Wo    = (const float*)d_in[6];  // (1024,1)
    const float* bo    = (const float*)d_in[7];  // (1)
    float* out = (float*)d_out;                  // (64,1)

    char* ws = (char*)d_ws;
    float* Sm     = (float*)(ws);                      // 64*128*4      = 32 KB
    float* G2     = (float*)(ws + (32u  << 10));       // 192*1024*4    = 768 KB
    float* z1part = (float*)(ws + (800u << 10));       // 16*64*1024*4  = 4 MB

    kB<<<769, 256, 0, stream>>>(x, masks, W0, Sm, G2);
    kF<<<512, 256, 0, stream>>>(G2, Sm, b0, W1, z1part);
    kE<<<64, 1024, 0, stream>>>(z1part, b1, Wo, bo, out);
}